// Round 3
// baseline (1655.421 us; speedup 1.0000x reference)
//
#include <hip/hip_runtime.h>

// GCN: out[m,n,o] = (A_hat relu(A_hat (x W1) + b1) W_out[m])[n,o] + b_out[m,o]
// A_hat = D^-1/2 (A + I) D^-1/2.
// Structure:
//  - deterministic radix-partition groups edges by 64-node dst-bucket
//    (block-local LDS histograms + 2-level scan -> exact disjoint ranges,
//    sequential writes, NO contended global atomics)
//  - propagate-1: per-bucket block, 64x128 fp32 LDS accumulator, ds_add_f32;
//    fused relu + 8-col projection (propagation linear in features)
//  - propagate-2 on the 8-col projection, per-bucket 64x8 LDS accumulator.

constexpr int CIN = 128;
constexpr int BSHIFT = 6;        // 64 nodes per bucket
constexpr int NBLKB = 64;        // partition blocks
constexpr int NBUK_MAX = 1024;   // LDS hist capacity (N<=65536)

// ---------- pass A: per-block bucket histogram + global degree count ----------
__global__ __launch_bounds__(256) void histbuck_k(const int* __restrict__ dst,
    int* __restrict__ cnt, int* __restrict__ blockhist, int E, int nbuk) {
  __shared__ int lh[NBUK_MAX];
  int b = blockIdx.x, t = threadIdx.x;
  for (int k = t; k < nbuk; k += 256) lh[k] = 0;
  __syncthreads();
  int per = (E + gridDim.x - 1) / gridDim.x;
  int s0 = b * per, s1 = min(E, s0 + per);
  for (int i = s0 + t; i < s1; i += 256) {
    int d = dst[i];
    atomicAdd(&cnt[d], 1);
    atomicAdd(&lh[d >> BSHIFT], 1);
  }
  __syncthreads();
  for (int k = t; k < nbuk; k += 256) blockhist[k * NBLKB + b] = lh[k];
}

__global__ void dinv_k(const int* __restrict__ cnt, float* __restrict__ dinv, int n) {
  int i = blockIdx.x * blockDim.x + threadIdx.x;
  if (i < n) dinv[i] = 1.0f / sqrtf((float)(cnt[i] + 1));  // +1 self-loop
}

// exclusive scan, chunk-wise; btot==nullptr for the top-level pass
__global__ __launch_bounds__(256) void scan_k(const int* __restrict__ v_in,
    int* __restrict__ excl_out, int* __restrict__ btot, int n) {
  __shared__ int wsum[4];
  int t = threadIdx.x, l = t & 63, w = t >> 6;
  int i = blockIdx.x * 256 + t;
  int v = (i < n) ? v_in[i] : 0;
  int orig = v;
  #pragma unroll
  for (int off = 1; off < 64; off <<= 1) {
    int u = __shfl_up(v, off);
    if (l >= off) v += u;
  }
  if (l == 63) wsum[w] = v;
  __syncthreads();
  int add = 0;
  #pragma unroll
  for (int j = 0; j < 4; ++j) if (j < w) add += wsum[j];
  v += add;
  if (i < n) excl_out[i] = v - orig;
  if (t == 255 && btot != nullptr) btot[blockIdx.x] = v;
}

__global__ void scanfix2_k(int* __restrict__ soff, const int* __restrict__ boff, int n) {
  int i = blockIdx.x * 256 + threadIdx.x;
  if (i < n) soff[i] += boff[blockIdx.x];
}

// ---------- pass B: write edges to exact (block,bucket) ranges ----------
__global__ __launch_bounds__(256) void stageB_k(const int* __restrict__ src,
    const int* __restrict__ dst, const int* __restrict__ soff,
    unsigned* __restrict__ stage, int E, int nbuk) {
  __shared__ int loff[NBUK_MAX];
  int b = blockIdx.x, t = threadIdx.x;
  for (int k = t; k < nbuk; k += 256) loff[k] = soff[k * NBLKB + b];
  __syncthreads();
  int per = (E + gridDim.x - 1) / gridDim.x;
  int s0 = b * per, s1 = min(E, s0 + per);
  for (int i = s0 + t; i < s1; i += 256) {
    int d = dst[i], s = src[i];
    int pos = atomicAdd(&loff[d >> BSHIFT], 1);
    stage[pos] = (unsigned)s | ((unsigned)(d & 63) << 17);  // src<2^17, dloc 6b
  }
}

// ---------- g = dinv[n] * (x @ W1), fp32 LDS-tiled ----------
__global__ __launch_bounds__(256) void gemm_k(const float* __restrict__ x,
    const float* __restrict__ W, const float* __restrict__ dinv,
    float* __restrict__ g, int nrows) {
  __shared__ float As[32][132];
  __shared__ float Bs[32][132];
  int t = threadIdx.x;
  int tx = t & 15, ty = t >> 4;
  int row0 = blockIdx.x * 128;
  float acc[8][8];
  #pragma unroll
  for (int i = 0; i < 8; ++i)
    #pragma unroll
    for (int j = 0; j < 8; ++j) acc[i][j] = 0.f;

  for (int kc = 0; kc < 4; ++kc) {
    int k0 = kc * 32;
    #pragma unroll
    for (int i = 0; i < 4; ++i) {
      int q = t + 256 * i;
      int kq = q & 7, r = q >> 3;
      int grow = row0 + r;
      float4 v = make_float4(0.f, 0.f, 0.f, 0.f);
      if (grow < nrows) v = *(const float4*)&x[grow * CIN + k0 + 4 * kq];
      As[4 * kq + 0][r] = v.x; As[4 * kq + 1][r] = v.y;
      As[4 * kq + 2][r] = v.z; As[4 * kq + 3][r] = v.w;
    }
    #pragma unroll
    for (int i = 0; i < 4; ++i) {
      int q = t + 256 * i;
      int c4 = q & 31, k = q >> 5;
      float4 v = *(const float4*)&W[(k0 + k) * CIN + 4 * c4];
      *(float4*)&Bs[k][4 * c4] = v;
    }
    __syncthreads();
    #pragma unroll
    for (int k = 0; k < 32; ++k) {
      float a[8], b[8];
      *(float4*)&a[0] = *(const float4*)&As[k][4 * ty];
      *(float4*)&a[4] = *(const float4*)&As[k][64 + 4 * ty];
      *(float4*)&b[0] = *(const float4*)&Bs[k][4 * tx];
      *(float4*)&b[4] = *(const float4*)&Bs[k][64 + 4 * tx];
      #pragma unroll
      for (int i = 0; i < 8; ++i)
        #pragma unroll
        for (int j = 0; j < 8; ++j) acc[i][j] = fmaf(a[i], b[j], acc[i][j]);
    }
    __syncthreads();
  }
  #pragma unroll
  for (int i = 0; i < 8; ++i) {
    int r = (i < 4) ? (4 * ty + i) : (64 + 4 * ty + (i - 4));
    int grow = row0 + r;
    if (grow < nrows) {
      float dv = dinv[grow];
      float4 o0 = make_float4(acc[i][0] * dv, acc[i][1] * dv, acc[i][2] * dv, acc[i][3] * dv);
      float4 o1 = make_float4(acc[i][4] * dv, acc[i][5] * dv, acc[i][6] * dv, acc[i][7] * dv);
      *(float4*)&g[grow * CIN + 4 * tx] = o0;
      *(float4*)&g[grow * CIN + 64 + 4 * tx] = o1;
    }
  }
}

// ---------- propagate-1: per-bucket LDS accumulate + fused epilogue ----------
__global__ __launch_bounds__(256) void prop1_k(const float* __restrict__ g,
    const unsigned* __restrict__ stage, const int* __restrict__ soff,
    const float* __restrict__ dinv, const float* __restrict__ b1,
    const float* __restrict__ Wout, float* __restrict__ g2,
    int N, int E, int nbuk) {
  __shared__ float h[64][128];   // bank(c) = c%32: lane l -> cols l, l+64 (2/bank, free)
  int k = blockIdx.x, t = threadIdx.x, l = t & 63, w = t >> 6;
  int nbase = k << 6;
  // init with self-loop term g[n] (dinv folded into g)
  for (int q = t; q < 2048; q += 256) {
    int loc = q >> 5, c4 = q & 31;
    int n = nbase + loc;
    float4 v = make_float4(0.f, 0.f, 0.f, 0.f);
    if (n < N) v = *(const float4*)&g[n * CIN + 4 * c4];
    *(float4*)&h[loc][4 * c4] = v;
  }
  __syncthreads();
  int r0 = soff[k * NBLKB];
  int r1 = (k + 1 < nbuk) ? soff[(k + 1) * NBLKB] : E;
  const float* gl = g + l;
  for (int base = r0 + 64 * w; base < r1; base += 256) {
    int cnt = min(64, r1 - base);
    unsigned eb = (base + l < r1) ? stage[base + l] : 0u;
    int i = 0;
    for (; i + 4 <= cnt; i += 4) {
      unsigned e0 = __shfl(eb, i),     e1 = __shfl(eb, i + 1);
      unsigned e2 = __shfl(eb, i + 2), e3 = __shfl(eb, i + 3);
      const float* p0 = &gl[(e0 & 0x1FFFF) * CIN];
      const float* p1 = &gl[(e1 & 0x1FFFF) * CIN];
      const float* p2 = &gl[(e2 & 0x1FFFF) * CIN];
      const float* p3 = &gl[(e3 & 0x1FFFF) * CIN];
      float a0 = p0[0], c0 = p0[64];
      float a1 = p1[0], c1 = p1[64];
      float a2 = p2[0], c2 = p2[64];
      float a3 = p3[0], c3 = p3[64];
      int d0 = e0 >> 17, d1 = e1 >> 17, d2 = e2 >> 17, d3 = e3 >> 17;
      atomicAdd(&h[d0][l], a0); atomicAdd(&h[d0][64 + l], c0);
      atomicAdd(&h[d1][l], a1); atomicAdd(&h[d1][64 + l], c1);
      atomicAdd(&h[d2][l], a2); atomicAdd(&h[d2][64 + l], c2);
      atomicAdd(&h[d3][l], a3); atomicAdd(&h[d3][64 + l], c3);
    }
    for (; i < cnt; ++i) {
      unsigned e0 = __shfl(eb, i);
      const float* p0 = &gl[(e0 & 0x1FFFF) * CIN];
      float a0 = p0[0], c0 = p0[64];
      int d0 = e0 >> 17;
      atomicAdd(&h[d0][l], a0); atomicAdd(&h[d0][64 + l], c0);
    }
  }
  __syncthreads();
  // epilogue: y = relu(dinv*h + b1); p = y @ W_cat; g2 = dinv * p
  float w0[8], w1[8];
  #pragma unroll
  for (int j = 0; j < 8; ++j) {
    w0[j] = Wout[(j >> 1) * 256 + 2 * l + (j & 1)];
    w1[j] = Wout[(j >> 1) * 256 + 128 + 2 * l + (j & 1)];
  }
  float bb0 = b1[l], bb1 = b1[64 + l];
  for (int nl = 16 * w; nl < 16 * w + 16; ++nl) {
    int n = nbase + nl;
    if (n >= N) break;
    float d = dinv[n];
    float y0 = fmaxf(fmaf(h[nl][l], d, bb0), 0.f);
    float y1 = fmaxf(fmaf(h[nl][64 + l], d, bb1), 0.f);
    float p[8];
    #pragma unroll
    for (int j = 0; j < 8; ++j) p[j] = fmaf(y0, w0[j], y1 * w1[j]);
    #pragma unroll
    for (int off = 1; off < 64; off <<= 1)
      #pragma unroll
      for (int j = 0; j < 8; ++j) p[j] += __shfl_xor(p[j], off);
    if (l < 8) {
      float v = (l == 0) ? p[0] : (l == 1) ? p[1] : (l == 2) ? p[2] : (l == 3) ? p[3]
              : (l == 4) ? p[4] : (l == 5) ? p[5] : (l == 6) ? p[6] : p[7];
      g2[n * 8 + l] = d * v;
    }
  }
}

// ---------- propagate-2 on 8 cols + bias ----------
__global__ __launch_bounds__(256) void prop2_k(const float* __restrict__ g2,
    const unsigned* __restrict__ stage, const int* __restrict__ soff,
    const float* __restrict__ dinv, const float* __restrict__ bout,
    float* __restrict__ out, int N, int E, int nbuk) {
  __shared__ float a2[64][8];
  int k = blockIdx.x, t = threadIdx.x, l = t & 63, w = t >> 6;
  int nbase = k << 6;
  for (int q = t; q < 512; q += 256) {
    int loc = q >> 3, f = q & 7;
    int n = nbase + loc;
    a2[loc][f] = (n < N) ? g2[n * 8 + f] : 0.f;   // self-loop term
  }
  __syncthreads();
  int r0 = soff[k * NBLKB];
  int r1 = (k + 1 < nbuk) ? soff[(k + 1) * NBLKB] : E;
  int f = l & 7;
  for (int base = r0 + 8 * w; base < r1; base += 32) {
    int e = base + (l >> 3);
    if (e < r1) {
      unsigned s = stage[e];
      int src = s & 0x1FFFF, dl = s >> 17;
      atomicAdd(&a2[dl][f], g2[src * 8 + f]);
    }
  }
  __syncthreads();
  for (int q = t; q < 512; q += 256) {
    int loc = q >> 3, ff = q & 7;
    int n = nbase + loc;
    if (n < N)
      out[(ff >> 1) * (2 * N) + 2 * n + (ff & 1)] = fmaf(dinv[n], a2[loc][ff], bout[ff]);
  }
}

extern "C" void kernel_launch(void* const* d_in, const int* in_sizes, int n_in,
                              void* d_out, int out_size, void* d_ws, size_t ws_size,
                              hipStream_t stream) {
  const float* x    = (const float*)d_in[0];
  const int*   ei   = (const int*)d_in[1];
  const float* W1   = (const float*)d_in[2];
  const float* b1   = (const float*)d_in[3];
  const float* Wout = (const float*)d_in[4];
  const float* bout = (const float*)d_in[5];
  float* out = (float*)d_out;

  const int N = in_sizes[0] / CIN;     // 50000
  const int E = in_sizes[1] / 2;       // 1600000
  const int* srcp = ei;
  const int* dstp = ei + E;
  const int NBUK = (N + 63) >> BSHIFT; // 782
  const int NSC = NBUK * NBLKB;        // 50048 scan entries

  char* ws = (char*)d_ws;
  size_t off = 0;
  auto alloc = [&](size_t bytes) -> void* {
    void* p = ws + off;
    off = (off + bytes + 511) & ~(size_t)511;
    return p;
  };
  float*    g         = (float*)alloc((size_t)N * CIN * 4);
  float*    g2        = (float*)alloc((size_t)N * 8 * 4);
  float*    dinv      = (float*)alloc((size_t)N * 4);
  int*      cnt       = (int*)alloc((size_t)N * 4);
  int*      blockhist = (int*)alloc((size_t)NSC * 4);
  int*      soff      = (int*)alloc((size_t)NSC * 4);
  int*      btot      = (int*)alloc(256 * 4);
  int*      boff      = (int*)alloc(256 * 4);
  unsigned* stage     = (unsigned*)alloc((size_t)E * 4);
  (void)ws_size; (void)n_in; (void)out_size;

  const int NB1 = (N + 255) / 256;
  const int NBS = (NSC + 255) / 256;   // 196 blocks

  hipMemsetAsync(cnt, 0, (size_t)N * 4, stream);
  histbuck_k<<<NBLKB, 256, 0, stream>>>(dstp, cnt, blockhist, E, NBUK);
  dinv_k<<<NB1, 256, 0, stream>>>(cnt, dinv, N);
  scan_k<<<NBS, 256, 0, stream>>>(blockhist, soff, btot, NSC);
  scan_k<<<1, 256, 0, stream>>>(btot, boff, nullptr, NBS);
  scanfix2_k<<<NBS, 256, 0, stream>>>(soff, boff, NSC);
  stageB_k<<<NBLKB, 256, 0, stream>>>(srcp, dstp, soff, stage, E, NBUK);

  gemm_k<<<(N + 127) / 128, 256, 0, stream>>>(x, W1, dinv, g, N);

  prop1_k<<<NBUK, 256, 0, stream>>>(g, stage, soff, dinv, b1, Wout, g2, N, E, NBUK);
  prop2_k<<<NBUK, 256, 0, stream>>>(g2, stage, soff, dinv, bout, out, N, E, NBUK);
}

// Round 4
// 216.951 us; speedup vs baseline: 7.6304x; 7.6304x over previous
//
#include <hip/hip_runtime.h>

// GCN: out[m,n,o] = (A_hat relu(A_hat (x W1) + b1) W_out[m])[n,o] + b_out[m,o]
// A_hat = D^-1/2 (A + I) D^-1/2.
// Structure (R4):
//  - deterministic radix partition by 64-node dst-bucket (LDS hists + 2-level
//    scan -> exact ranges, sequential writes), then per-bucket csrloc_k sorts
//    to per-node CSR (writes stay in the bucket's 8KB L2 window) and computes
//    degrees/dinv from the partitioned stage (no random global atomics).
//  - g = bf16(dinv * (x@W1)): 256B rows halve the prop1 gather traffic.
//  - prop1: R1-style full-occupancy register-accum gather (8192 waves, 8-deep
//    ILP), fused relu + 8-col projection (propagation linear in features).
//  - g2 bf16 (800KB, L2-resident) -> prop2 gather is L2-served.

constexpr int CIN = 128;
constexpr int BSHIFT = 6;        // 64 nodes per bucket
constexpr int NBLKB = 64;        // partition blocks
constexpr int NBUK_MAX = 1024;   // LDS hist capacity (N<=65536)

__device__ inline unsigned pack_bf16x2(float a, float b) {
  unsigned ua = __float_as_uint(a), ub = __float_as_uint(b);
  ua = (ua + 0x7FFFu + ((ua >> 16) & 1u)) >> 16;
  ub = (ub + 0x7FFFu + ((ub >> 16) & 1u)) >> 16;
  return ua | (ub << 16);
}
__device__ inline unsigned short pack_bf16(float a) {
  unsigned ua = __float_as_uint(a);
  return (unsigned short)((ua + 0x7FFFu + ((ua >> 16) & 1u)) >> 16);
}
__device__ inline float bf_lo(unsigned u) { return __uint_as_float(u << 16); }
__device__ inline float bf_hi(unsigned u) { return __uint_as_float(u & 0xFFFF0000u); }

// ---------- pass A: per-block bucket histogram (LDS only) ----------
__global__ __launch_bounds__(256) void histbuck_k(const int* __restrict__ dst,
    int* __restrict__ blockhist, int E, int nbuk) {
  __shared__ int lh[NBUK_MAX];
  int b = blockIdx.x, t = threadIdx.x;
  for (int k = t; k < nbuk; k += 256) lh[k] = 0;
  __syncthreads();
  int per = (E + gridDim.x - 1) / gridDim.x;
  int s0 = b * per, s1 = min(E, s0 + per);
  for (int i = s0 + t; i < s1; i += 256) atomicAdd(&lh[dst[i] >> BSHIFT], 1);
  __syncthreads();
  for (int k = t; k < nbuk; k += 256) blockhist[k * NBLKB + b] = lh[k];
}

// exclusive scan, chunk-wise; btot==nullptr for the top-level pass
__global__ __launch_bounds__(256) void scan_k(const int* __restrict__ v_in,
    int* __restrict__ excl_out, int* __restrict__ btot, int n) {
  __shared__ int wsum[4];
  int t = threadIdx.x, l = t & 63, w = t >> 6;
  int i = blockIdx.x * 256 + t;
  int v = (i < n) ? v_in[i] : 0;
  int orig = v;
  #pragma unroll
  for (int off = 1; off < 64; off <<= 1) {
    int u = __shfl_up(v, off);
    if (l >= off) v += u;
  }
  if (l == 63) wsum[w] = v;
  __syncthreads();
  int add = 0;
  #pragma unroll
  for (int j = 0; j < 4; ++j) if (j < w) add += wsum[j];
  v += add;
  if (i < n) excl_out[i] = v - orig;
  if (t == 255 && btot != nullptr) btot[blockIdx.x] = v;
}

__global__ void scanfix2_k(int* __restrict__ soff, const int* __restrict__ boff, int n) {
  int i = blockIdx.x * 256 + threadIdx.x;
  if (i < n) soff[i] += boff[blockIdx.x];
}

// ---------- pass B: write edges to exact (block,bucket) ranges ----------
__global__ __launch_bounds__(256) void stageB_k(const int* __restrict__ src,
    const int* __restrict__ dst, const int* __restrict__ soff,
    unsigned* __restrict__ stage, int E, int nbuk) {
  __shared__ int loff[NBUK_MAX];
  int b = blockIdx.x, t = threadIdx.x;
  for (int k = t; k < nbuk; k += 256) loff[k] = soff[k * NBLKB + b];
  __syncthreads();
  int per = (E + gridDim.x - 1) / gridDim.x;
  int s0 = b * per, s1 = min(E, s0 + per);
  for (int i = s0 + t; i < s1; i += 256) {
    int d = dst[i], s = src[i];
    int pos = atomicAdd(&loff[d >> BSHIFT], 1);
    stage[pos] = (unsigned)s | ((unsigned)(d & 63) << 17);  // src<2^17, dloc 6b
  }
}

// ---------- per-bucket: stage -> per-node CSR + degrees + dinv ----------
__global__ __launch_bounds__(256) void csrloc_k(const unsigned* __restrict__ stage,
    const int* __restrict__ soff, int* __restrict__ row_ptr, int* __restrict__ csr,
    float* __restrict__ dinv, int N, int E, int nbuk) {
  __shared__ int cnt64[64], off64[64], cur64[64];
  int k = blockIdx.x, t = threadIdx.x;
  if (t < 64) { cnt64[t] = 0; cur64[t] = 0; }
  __syncthreads();
  int r0 = soff[k * NBLKB];
  int r1 = (k + 1 < nbuk) ? soff[(k + 1) * NBLKB] : E;
  for (int i = r0 + t; i < r1; i += 256) atomicAdd(&cnt64[stage[i] >> 17], 1);
  __syncthreads();
  if (t < 64) {
    int v = cnt64[t], orig = v;
    #pragma unroll
    for (int off = 1; off < 64; off <<= 1) {
      int u = __shfl_up(v, off);
      if (t >= off) v += u;
    }
    off64[t] = v - orig;
    int n = (k << BSHIFT) + t;
    if (n < N) {
      row_ptr[n] = r0 + v - orig;
      dinv[n] = rsqrtf((float)(orig + 1));
    }
    if (n == N - 1 || (k == nbuk - 1 && t == 63)) row_ptr[N] = E;
  }
  __syncthreads();
  for (int i = r0 + t; i < r1; i += 256) {
    unsigned s = stage[i];
    int dl = s >> 17;
    int pos = r0 + off64[dl] + atomicAdd(&cur64[dl], 1);
    csr[pos] = s & 0x1FFFF;
  }
}

// ---------- g(bf16) = dinv[n] * (x @ W1), fp32 LDS-tiled ----------
__global__ __launch_bounds__(256) void gemm_k(const float* __restrict__ x,
    const float* __restrict__ W, const float* __restrict__ dinv,
    unsigned* __restrict__ gu, int nrows) {
  __shared__ float As[32][132];
  __shared__ float Bs[32][132];
  int t = threadIdx.x;
  int tx = t & 15, ty = t >> 4;
  int row0 = blockIdx.x * 128;
  float acc[8][8];
  #pragma unroll
  for (int i = 0; i < 8; ++i)
    #pragma unroll
    for (int j = 0; j < 8; ++j) acc[i][j] = 0.f;

  for (int kc = 0; kc < 4; ++kc) {
    int k0 = kc * 32;
    #pragma unroll
    for (int i = 0; i < 4; ++i) {
      int q = t + 256 * i;
      int kq = q & 7, r = q >> 3;
      int grow = row0 + r;
      float4 v = make_float4(0.f, 0.f, 0.f, 0.f);
      if (grow < nrows) v = *(const float4*)&x[grow * CIN + k0 + 4 * kq];
      As[4 * kq + 0][r] = v.x; As[4 * kq + 1][r] = v.y;
      As[4 * kq + 2][r] = v.z; As[4 * kq + 3][r] = v.w;
    }
    #pragma unroll
    for (int i = 0; i < 4; ++i) {
      int q = t + 256 * i;
      int c4 = q & 31, k = q >> 5;
      float4 v = *(const float4*)&W[(k0 + k) * CIN + 4 * c4];
      *(float4*)&Bs[k][4 * c4] = v;
    }
    __syncthreads();
    #pragma unroll
    for (int k = 0; k < 32; ++k) {
      float a[8], b[8];
      *(float4*)&a[0] = *(const float4*)&As[k][4 * ty];
      *(float4*)&a[4] = *(const float4*)&As[k][64 + 4 * ty];
      *(float4*)&b[0] = *(const float4*)&Bs[k][4 * tx];
      *(float4*)&b[4] = *(const float4*)&Bs[k][64 + 4 * tx];
      #pragma unroll
      for (int i = 0; i < 8; ++i)
        #pragma unroll
        for (int j = 0; j < 8; ++j) acc[i][j] = fmaf(a[i], b[j], acc[i][j]);
    }
    __syncthreads();
  }
  #pragma unroll
  for (int i = 0; i < 8; ++i) {
    int r = (i < 4) ? (4 * ty + i) : (64 + 4 * ty + (i - 4));
    int grow = row0 + r;
    if (grow < nrows) {
      float dv = dinv[grow];
      uint2 o0 = make_uint2(pack_bf16x2(acc[i][0] * dv, acc[i][1] * dv),
                            pack_bf16x2(acc[i][2] * dv, acc[i][3] * dv));
      uint2 o1 = make_uint2(pack_bf16x2(acc[i][4] * dv, acc[i][5] * dv),
                            pack_bf16x2(acc[i][6] * dv, acc[i][7] * dv));
      *(uint2*)&gu[grow * 64 + 2 * tx] = o0;
      *(uint2*)&gu[grow * 64 + 32 + 2 * tx] = o1;
    }
  }
}

// ---------- propagate-1: full-occupancy register gather + fused epilogue ----------
__global__ __launch_bounds__(256) void prop1_k(const unsigned* __restrict__ gu,
    const int* __restrict__ row_ptr, const int* __restrict__ csr,
    const float* __restrict__ dinv, const float* __restrict__ b1,
    const float* __restrict__ Wout, unsigned short* __restrict__ g2u,
    int n_nodes, int n_waves) {
  int l = threadIdx.x & 63;
  int wid = (blockIdx.x * blockDim.x + threadIdx.x) >> 6;
  // lane l owns cols 2l, 2l+1 (one packed bf16x2 per row)
  float w0[8], w1[8];
  #pragma unroll
  for (int j = 0; j < 8; ++j) {
    w0[j] = Wout[(j >> 1) * 256 + 4 * l + (j & 1)];
    w1[j] = Wout[(j >> 1) * 256 + 4 * l + 2 + (j & 1)];
  }
  float bb0 = b1[2 * l], bb1 = b1[2 * l + 1];
  const unsigned* gl = gu + l;

  for (int n = wid; n < n_nodes; n += n_waves) {
    int start = row_ptr[n], end = row_ptr[n + 1];
    float d = dinv[n];
    unsigned us = gl[n * 64];          // self-loop (dinv folded in g)
    float ax = bf_lo(us), ay = bf_hi(us);
    for (int base = start; base < end; base += 64) {
      int cnt = min(64, end - base);
      int eb = (base + l < end) ? csr[base + l] : 0;
      int i = 0;
      for (; i + 8 <= cnt; i += 8) {
        int s0 = __shfl(eb, i),     s1 = __shfl(eb, i + 1);
        int s2 = __shfl(eb, i + 2), s3 = __shfl(eb, i + 3);
        int s4 = __shfl(eb, i + 4), s5 = __shfl(eb, i + 5);
        int s6 = __shfl(eb, i + 6), s7 = __shfl(eb, i + 7);
        unsigned u0 = gl[s0 * 64], u1 = gl[s1 * 64];
        unsigned u2 = gl[s2 * 64], u3 = gl[s3 * 64];
        unsigned u4 = gl[s4 * 64], u5 = gl[s5 * 64];
        unsigned u6 = gl[s6 * 64], u7 = gl[s7 * 64];
        ax += (bf_lo(u0) + bf_lo(u1)) + (bf_lo(u2) + bf_lo(u3))
            + (bf_lo(u4) + bf_lo(u5)) + (bf_lo(u6) + bf_lo(u7));
        ay += (bf_hi(u0) + bf_hi(u1)) + (bf_hi(u2) + bf_hi(u3))
            + (bf_hi(u4) + bf_hi(u5)) + (bf_hi(u6) + bf_hi(u7));
      }
      for (; i < cnt; ++i) {
        int s = __shfl(eb, i);
        unsigned u = gl[s * 64];
        ax += bf_lo(u); ay += bf_hi(u);
      }
    }
    float y0 = fmaxf(fmaf(ax, d, bb0), 0.f);
    float y1 = fmaxf(fmaf(ay, d, bb1), 0.f);
    float p[8];
    #pragma unroll
    for (int j = 0; j < 8; ++j) p[j] = fmaf(y0, w0[j], y1 * w1[j]);
    #pragma unroll
    for (int off = 1; off < 64; off <<= 1)
      #pragma unroll
      for (int j = 0; j < 8; ++j) p[j] += __shfl_xor(p[j], off);
    if (l < 8) {
      float v = (l == 0) ? p[0] : (l == 1) ? p[1] : (l == 2) ? p[2] : (l == 3) ? p[3]
              : (l == 4) ? p[4] : (l == 5) ? p[5] : (l == 6) ? p[6] : p[7];
      g2u[n * 8 + l] = pack_bf16(d * v);
    }
  }
}

// ---------- propagate-2 on 8 bf16 cols + bias ----------
__global__ __launch_bounds__(256) void prop2_k(const unsigned short* __restrict__ g2u,
    const int* __restrict__ row_ptr, const int* __restrict__ csr,
    const float* __restrict__ dinv, const float* __restrict__ bout,
    float* __restrict__ out, int n_nodes, int n_groups) {
  int tid = blockIdx.x * blockDim.x + threadIdx.x;
  int gidx = tid >> 3;
  int f = tid & 7;
  float bo = bout[f];
  for (int n = gidx; n < n_nodes; n += n_groups) {
    int start = row_ptr[n], end = row_ptr[n + 1];
    float acc = __uint_as_float(((unsigned)g2u[n * 8 + f]) << 16);  // self-loop
    for (int e = start; e < end; ++e) {
      int s = csr[e];
      acc += __uint_as_float(((unsigned)g2u[s * 8 + f]) << 16);
    }
    out[(f >> 1) * (2 * n_nodes) + n * 2 + (f & 1)] = fmaf(dinv[n], acc, bo);
  }
}

extern "C" void kernel_launch(void* const* d_in, const int* in_sizes, int n_in,
                              void* d_out, int out_size, void* d_ws, size_t ws_size,
                              hipStream_t stream) {
  const float* x    = (const float*)d_in[0];
  const int*   ei   = (const int*)d_in[1];
  const float* W1   = (const float*)d_in[2];
  const float* b1   = (const float*)d_in[3];
  const float* Wout = (const float*)d_in[4];
  const float* bout = (const float*)d_in[5];
  float* out = (float*)d_out;

  const int N = in_sizes[0] / CIN;     // 50000
  const int E = in_sizes[1] / 2;       // 1600000
  const int* srcp = ei;
  const int* dstp = ei + E;
  const int NBUK = (N + 63) >> BSHIFT; // 782
  const int NSC = NBUK * NBLKB;        // 50048 scan entries

  char* ws = (char*)d_ws;
  size_t off = 0;
  auto alloc = [&](size_t bytes) -> void* {
    void* p = ws + off;
    off = (off + bytes + 511) & ~(size_t)511;
    return p;
  };
  unsigned*       gu        = (unsigned*)alloc((size_t)N * 64 * 4);      // bf16 g
  unsigned short* g2u       = (unsigned short*)alloc((size_t)N * 8 * 2); // bf16 g2
  float*          dinv      = (float*)alloc((size_t)N * 4);
  int*            blockhist = (int*)alloc((size_t)NSC * 4);
  int*            soff      = (int*)alloc((size_t)NSC * 4);
  int*            btot      = (int*)alloc(256 * 4);
  int*            boff      = (int*)alloc(256 * 4);
  int*            row_ptr   = (int*)alloc((size_t)(N + 1) * 4);
  int*            csr       = (int*)alloc((size_t)E * 4);
  unsigned*       stage     = (unsigned*)alloc((size_t)E * 4);
  (void)ws_size; (void)n_in; (void)out_size;

  const int NBS = (NSC + 255) / 256;   // 196 blocks (<=256)

  histbuck_k<<<NBLKB, 256, 0, stream>>>(dstp, blockhist, E, NBUK);
  scan_k<<<NBS, 256, 0, stream>>>(blockhist, soff, btot, NSC);
  scan_k<<<1, 256, 0, stream>>>(btot, boff, nullptr, NBS);
  scanfix2_k<<<NBS, 256, 0, stream>>>(soff, boff, NSC);
  stageB_k<<<NBLKB, 256, 0, stream>>>(srcp, dstp, soff, stage, E, NBUK);
  csrloc_k<<<NBUK, 256, 0, stream>>>(stage, soff, row_ptr, csr, dinv, N, E, NBUK);

  gemm_k<<<(N + 127) / 128, 256, 0, stream>>>(x, W1, dinv, gu, N);

  const int P1_BLOCKS = 2048;
  prop1_k<<<P1_BLOCKS, 256, 0, stream>>>(gu, row_ptr, csr, dinv, b1, Wout, g2u,
                                         N, P1_BLOCKS * 4);
  const int P2_BLOCKS = 512;
  prop2_k<<<P2_BLOCKS, 256, 0, stream>>>(g2u, row_ptr, csr, dinv, bout, out,
                                         N, P2_BLOCKS * 32);
}

// Round 5
// 151.184 us; speedup vs baseline: 10.9497x; 1.4350x over previous
//
#include <hip/hip_runtime.h>

// GCN: out[m,n,o] = (A_hat relu(A_hat (x W1) + b1) W_out[m])[n,o] + b_out[m,o]
// A_hat = D^-1/2 (A + I) D^-1/2.
// R5 structure:
//  - 256-block radix partition by 64-node dst-bucket (full-machine grids),
//    2-level scan (level-2 = one 1024-thread block), LDS-staged per-bucket
//    count-sort -> per-node CSR with coalesced writes + dinv.
//  - g = bf16(dinv * (x@W1)) [fp32 LDS gemm]: 256B rows.
//  - prop1: full-occupancy gather, 16 lanes x uint4 per row (4 edges per
//    load-inst), fused relu + 8-col projection per sub-wave.
//  - g2 bf16 (800KB, L2-resident) -> prop2 gather L2-served.

constexpr int CIN = 128;
constexpr int BSHIFT = 6;        // 64 nodes per bucket
constexpr int NBLKB = 256;       // partition blocks
constexpr int NBUK_MAX = 1024;   // LDS hist capacity (N<=65536)
constexpr int CSR_CAP = 4096;    // LDS bucket-sort capacity (mean ~2048, std ~45)

__device__ inline unsigned pack_bf16x2(float a, float b) {
  unsigned ua = __float_as_uint(a), ub = __float_as_uint(b);
  ua = (ua + 0x7FFFu + ((ua >> 16) & 1u)) >> 16;
  ub = (ub + 0x7FFFu + ((ub >> 16) & 1u)) >> 16;
  return ua | (ub << 16);
}
__device__ inline float bf_lo(unsigned u) { return __uint_as_float(u << 16); }
__device__ inline float bf_hi(unsigned u) { return __uint_as_float(u & 0xFFFF0000u); }

// ---------- pass A: per-block bucket histogram (LDS only) ----------
__global__ __launch_bounds__(256) void histbuck_k(const int* __restrict__ dst,
    int* __restrict__ blockhist, int E, int nbuk) {
  __shared__ int lh[NBUK_MAX];
  int b = blockIdx.x, t = threadIdx.x;
  for (int k = t; k < nbuk; k += 256) lh[k] = 0;
  __syncthreads();
  int per = (E + gridDim.x - 1) / gridDim.x;
  int s0 = b * per, s1 = min(E, s0 + per);
  for (int i = s0 + t; i < s1; i += 256) atomicAdd(&lh[dst[i] >> BSHIFT], 1);
  __syncthreads();
  for (int k = t; k < nbuk; k += 256) blockhist[k * NBLKB + b] = lh[k];
}

// exclusive scan, blockDim-agnostic (256 or 1024); btot==nullptr for top level
__global__ void scan_k(const int* __restrict__ v_in,
    int* __restrict__ excl_out, int* __restrict__ btot, int n) {
  __shared__ int wsum[16];
  int t = threadIdx.x, l = t & 63, w = t >> 6;
  int nw = blockDim.x >> 6;
  int i = blockIdx.x * blockDim.x + t;
  int v = (i < n) ? v_in[i] : 0;
  int orig = v;
  #pragma unroll
  for (int off = 1; off < 64; off <<= 1) {
    int u = __shfl_up(v, off);
    if (l >= off) v += u;
  }
  if (l == 63) wsum[w] = v;
  __syncthreads();
  int add = 0;
  for (int j = 0; j < nw; ++j) if (j < w) add += wsum[j];
  v += add;
  if (i < n) excl_out[i] = v - orig;
  if (t == (int)blockDim.x - 1 && btot != nullptr) btot[blockIdx.x] = v;
}

__global__ void scanfix2_k(int* __restrict__ soff, const int* __restrict__ boff, int n) {
  int i = blockIdx.x * 256 + threadIdx.x;
  if (i < n) soff[i] += boff[blockIdx.x];
}

// ---------- pass B: write edges to exact (block,bucket) ranges ----------
__global__ __launch_bounds__(256) void stageB_k(const int* __restrict__ src,
    const int* __restrict__ dst, const int* __restrict__ soff,
    unsigned* __restrict__ stage, int E, int nbuk) {
  __shared__ int loff[NBUK_MAX];
  int b = blockIdx.x, t = threadIdx.x;
  for (int k = t; k < nbuk; k += 256) loff[k] = soff[k * NBLKB + b];
  __syncthreads();
  int per = (E + gridDim.x - 1) / gridDim.x;
  int s0 = b * per, s1 = min(E, s0 + per);
  for (int i = s0 + t; i < s1; i += 256) {
    int d = dst[i], s = src[i];
    int pos = atomicAdd(&loff[d >> BSHIFT], 1);
    stage[pos] = (unsigned)s | ((unsigned)(d & 63) << 17);  // src<2^17, dloc 6b
  }
}

// ---------- per-bucket LDS count-sort: stage -> per-node CSR + dinv ----------
__global__ __launch_bounds__(256) void csrloc_k(const unsigned* __restrict__ stage,
    const int* __restrict__ soff, int* __restrict__ row_ptr, int* __restrict__ csr,
    float* __restrict__ dinv, int N, int E, int nbuk) {
  __shared__ int cnt64[64], off64[64], cur64[64];
  __shared__ unsigned ebuf[CSR_CAP];
  __shared__ int sbuf[CSR_CAP];
  int k = blockIdx.x, t = threadIdx.x;
  if (t < 64) { cnt64[t] = 0; cur64[t] = 0; }
  __syncthreads();
  int r0 = soff[k * NBLKB];
  int r1 = (k + 1 < nbuk) ? soff[(k + 1) * NBLKB] : E;
  int len = r1 - r0;
  if (len <= CSR_CAP) {
    for (int i = t; i < len; i += 256) {
      unsigned s = stage[r0 + i];
      ebuf[i] = s;
      atomicAdd(&cnt64[s >> 17], 1);
    }
    __syncthreads();
    if (t < 64) {
      int v = cnt64[t], orig = v;
      #pragma unroll
      for (int off = 1; off < 64; off <<= 1) {
        int u = __shfl_up(v, off);
        if (t >= off) v += u;
      }
      off64[t] = v - orig;
      int n = (k << BSHIFT) + t;
      if (n < N) {
        row_ptr[n] = r0 + v - orig;
        dinv[n] = rsqrtf((float)(orig + 1));
      }
      if (k == nbuk - 1 && t == 63) row_ptr[N] = E;
    }
    __syncthreads();
    for (int i = t; i < len; i += 256) {
      unsigned s = ebuf[i];
      int dl = s >> 17;
      int pos = off64[dl] + atomicAdd(&cur64[dl], 1);
      sbuf[pos] = (int)(s & 0x1FFFF);
    }
    __syncthreads();
    for (int i = t; i < len; i += 256) csr[r0 + i] = sbuf[i];
  } else {  // fallback (statistically never at E/N=32)
    for (int i = r0 + t; i < r1; i += 256) atomicAdd(&cnt64[stage[i] >> 17], 1);
    __syncthreads();
    if (t < 64) {
      int v = cnt64[t], orig = v;
      #pragma unroll
      for (int off = 1; off < 64; off <<= 1) {
        int u = __shfl_up(v, off);
        if (t >= off) v += u;
      }
      off64[t] = v - orig;
      int n = (k << BSHIFT) + t;
      if (n < N) {
        row_ptr[n] = r0 + v - orig;
        dinv[n] = rsqrtf((float)(orig + 1));
      }
      if (k == nbuk - 1 && t == 63) row_ptr[N] = E;
    }
    __syncthreads();
    for (int i = r0 + t; i < r1; i += 256) {
      unsigned s = stage[i];
      int dl = s >> 17;
      int pos = r0 + off64[dl] + atomicAdd(&cur64[dl], 1);
      csr[pos] = (int)(s & 0x1FFFF);
    }
  }
}

// ---------- g(bf16) = dinv[n] * (x @ W1), fp32 LDS-tiled ----------
__global__ __launch_bounds__(256) void gemm_k(const float* __restrict__ x,
    const float* __restrict__ W, const float* __restrict__ dinv,
    unsigned* __restrict__ gu, int nrows) {
  __shared__ float As[32][132];
  __shared__ float Bs[32][132];
  int t = threadIdx.x;
  int tx = t & 15, ty = t >> 4;
  int row0 = blockIdx.x * 128;
  float acc[8][8];
  #pragma unroll
  for (int i = 0; i < 8; ++i)
    #pragma unroll
    for (int j = 0; j < 8; ++j) acc[i][j] = 0.f;

  for (int kc = 0; kc < 4; ++kc) {
    int k0 = kc * 32;
    #pragma unroll
    for (int i = 0; i < 4; ++i) {
      int q = t + 256 * i;
      int kq = q & 7, r = q >> 3;
      int grow = row0 + r;
      float4 v = make_float4(0.f, 0.f, 0.f, 0.f);
      if (grow < nrows) v = *(const float4*)&x[grow * CIN + k0 + 4 * kq];
      As[4 * kq + 0][r] = v.x; As[4 * kq + 1][r] = v.y;
      As[4 * kq + 2][r] = v.z; As[4 * kq + 3][r] = v.w;
    }
    #pragma unroll
    for (int i = 0; i < 4; ++i) {
      int q = t + 256 * i;
      int c4 = q & 31, k = q >> 5;
      float4 v = *(const float4*)&W[(k0 + k) * CIN + 4 * c4];
      *(float4*)&Bs[k][4 * c4] = v;
    }
    __syncthreads();
    #pragma unroll
    for (int k = 0; k < 32; ++k) {
      float a[8], b[8];
      *(float4*)&a[0] = *(const float4*)&As[k][4 * ty];
      *(float4*)&a[4] = *(const float4*)&As[k][64 + 4 * ty];
      *(float4*)&b[0] = *(const float4*)&Bs[k][4 * tx];
      *(float4*)&b[4] = *(const float4*)&Bs[k][64 + 4 * tx];
      #pragma unroll
      for (int i = 0; i < 8; ++i)
        #pragma unroll
        for (int j = 0; j < 8; ++j) acc[i][j] = fmaf(a[i], b[j], acc[i][j]);
    }
    __syncthreads();
  }
  #pragma unroll
  for (int i = 0; i < 8; ++i) {
    int r = (i < 4) ? (4 * ty + i) : (64 + 4 * ty + (i - 4));
    int grow = row0 + r;
    if (grow < nrows) {
      float dv = dinv[grow];
      uint2 o0 = make_uint2(pack_bf16x2(acc[i][0] * dv, acc[i][1] * dv),
                            pack_bf16x2(acc[i][2] * dv, acc[i][3] * dv));
      uint2 o1 = make_uint2(pack_bf16x2(acc[i][4] * dv, acc[i][5] * dv),
                            pack_bf16x2(acc[i][6] * dv, acc[i][7] * dv));
      *(uint2*)&gu[grow * 64 + 2 * tx] = o0;
      *(uint2*)&gu[grow * 64 + 32 + 2 * tx] = o1;
    }
  }
}

// ---------- propagate-1: 16-lane x uint4 row gather + fused epilogue ----------
#define ACC8(U) do { \
  acc[0] += bf_lo((U).x); acc[1] += bf_hi((U).x); \
  acc[2] += bf_lo((U).y); acc[3] += bf_hi((U).y); \
  acc[4] += bf_lo((U).z); acc[5] += bf_hi((U).z); \
  acc[6] += bf_lo((U).w); acc[7] += bf_hi((U).w); } while (0)

__global__ __launch_bounds__(256) void prop1_k(const uint4* __restrict__ g4,
    const int* __restrict__ row_ptr, const int* __restrict__ csr,
    const float* __restrict__ dinv, const float* __restrict__ b1,
    const float* __restrict__ Wout, unsigned* __restrict__ g2w,
    int n_nodes, int n_waves) {
  int l = threadIdx.x & 63;
  int q = l & 15, sub = l >> 4;     // lane q covers cols 8q..8q+7; sub owns j=2sub,2sub+1
  int wid = (blockIdx.x * blockDim.x + threadIdx.x) >> 6;
  float wj0[8], wj1[8], bb[8];
  #pragma unroll
  for (int c = 0; c < 8; ++c) {
    int col = 8 * q + c;
    wj0[c] = Wout[sub * 256 + col * 2];
    wj1[c] = Wout[sub * 256 + col * 2 + 1];
    bb[c] = b1[col];
  }
  for (int n = wid; n < n_nodes; n += n_waves) {
    int start = row_ptr[n], end = row_ptr[n + 1];
    float d = dinv[n];
    float acc[8];
    #pragma unroll
    for (int c = 0; c < 8; ++c) acc[c] = 0.f;
    for (int base = start; base < end; base += 64) {
      int cnt = min(64, end - base);
      int eb = (base + l < end) ? csr[base + l] : 0;
      int i = 0;
      for (; i + 16 <= cnt; i += 16) {
        int s0 = __shfl(eb, i + sub);
        int s1 = __shfl(eb, i + 4 + sub);
        int s2 = __shfl(eb, i + 8 + sub);
        int s3 = __shfl(eb, i + 12 + sub);
        uint4 u0 = g4[s0 * 16 + q];
        uint4 u1 = g4[s1 * 16 + q];
        uint4 u2 = g4[s2 * 16 + q];
        uint4 u3 = g4[s3 * 16 + q];
        ACC8(u0); ACC8(u1); ACC8(u2); ACC8(u3);
      }
      for (; i + 4 <= cnt; i += 4) {
        int s0 = __shfl(eb, i + sub);
        uint4 u0 = g4[s0 * 16 + q];
        ACC8(u0);
      }
      if (i < cnt) {
        int idx = i + sub;
        bool vld = idx < cnt;
        int s0 = __shfl(eb, vld ? idx : i);
        uint4 u0 = g4[s0 * 16 + q];
        if (vld) { ACC8(u0); }
      }
    }
    #pragma unroll
    for (int c = 0; c < 8; ++c) {   // merge the 4 sub-waves
      acc[c] += __shfl_xor(acc[c], 16);
      acc[c] += __shfl_xor(acc[c], 32);
    }
    uint4 us = g4[n * 16 + q];       // self-loop (dinv folded in g)
    ACC8(us);
    float p0 = 0.f, p1 = 0.f;
    #pragma unroll
    for (int c = 0; c < 8; ++c) {
      float y = fmaxf(fmaf(acc[c], d, bb[c]), 0.f);
      p0 = fmaf(y, wj0[c], p0);
      p1 = fmaf(y, wj1[c], p1);
    }
    #pragma unroll
    for (int off = 1; off < 16; off <<= 1) {
      p0 += __shfl_xor(p0, off);
      p1 += __shfl_xor(p1, off);
    }
    if (q == 0) g2w[n * 4 + sub] = pack_bf16x2(d * p0, d * p1);
  }
}

// ---------- propagate-2 on 8 bf16 cols + bias ----------
__global__ __launch_bounds__(256) void prop2_k(const unsigned short* __restrict__ g2u,
    const int* __restrict__ row_ptr, const int* __restrict__ csr,
    const float* __restrict__ dinv, const float* __restrict__ bout,
    float* __restrict__ out, int n_nodes, int n_groups) {
  int tid = blockIdx.x * blockDim.x + threadIdx.x;
  int gidx = tid >> 3;
  int f = tid & 7;
  float bo = bout[f];
  for (int n = gidx; n < n_nodes; n += n_groups) {
    int start = row_ptr[n], end = row_ptr[n + 1];
    float acc = __uint_as_float(((unsigned)g2u[n * 8 + f]) << 16);  // self-loop
    for (int e = start; e < end; ++e) {
      int s = csr[e];
      acc += __uint_as_float(((unsigned)g2u[s * 8 + f]) << 16);
    }
    out[(f >> 1) * (2 * n_nodes) + n * 2 + (f & 1)] = fmaf(dinv[n], acc, bo);
  }
}

extern "C" void kernel_launch(void* const* d_in, const int* in_sizes, int n_in,
                              void* d_out, int out_size, void* d_ws, size_t ws_size,
                              hipStream_t stream) {
  const float* x    = (const float*)d_in[0];
  const int*   ei   = (const int*)d_in[1];
  const float* W1   = (const float*)d_in[2];
  const float* b1   = (const float*)d_in[3];
  const float* Wout = (const float*)d_in[4];
  const float* bout = (const float*)d_in[5];
  float* out = (float*)d_out;

  const int N = in_sizes[0] / CIN;     // 50000
  const int E = in_sizes[1] / 2;       // 1600000
  const int* srcp = ei;
  const int* dstp = ei + E;
  const int NBUK = (N + 63) >> BSHIFT; // 782
  const int NSC = NBUK * NBLKB;        // 200192 scan entries

  char* ws = (char*)d_ws;
  size_t off = 0;
  auto alloc = [&](size_t bytes) -> void* {
    void* p = ws + off;
    off = (off + bytes + 511) & ~(size_t)511;
    return p;
  };
  unsigned*       gu        = (unsigned*)alloc((size_t)N * 64 * 4);      // bf16 g
  unsigned short* g2u       = (unsigned short*)alloc((size_t)N * 8 * 2); // bf16 g2
  float*          dinv      = (float*)alloc((size_t)N * 4);
  int*            blockhist = (int*)alloc((size_t)NSC * 4);
  int*            soff      = (int*)alloc((size_t)NSC * 4);
  int*            btot      = (int*)alloc((size_t)NBUK_MAX * 4);
  int*            boff      = (int*)alloc((size_t)NBUK_MAX * 4);
  int*            row_ptr   = (int*)alloc((size_t)(N + 1) * 4);
  int*            csr       = (int*)alloc((size_t)E * 4);
  unsigned*       stage     = (unsigned*)alloc((size_t)E * 4);
  (void)ws_size; (void)n_in; (void)out_size;

  histbuck_k<<<NBLKB, 256, 0, stream>>>(dstp, blockhist, E, NBUK);
  scan_k<<<NBUK, 256, 0, stream>>>(blockhist, soff, btot, NSC);     // level 1
  scan_k<<<1, 1024, 0, stream>>>(btot, boff, nullptr, NBUK);        // level 2
  scanfix2_k<<<NBUK, 256, 0, stream>>>(soff, boff, NSC);
  stageB_k<<<NBLKB, 256, 0, stream>>>(srcp, dstp, soff, stage, E, NBUK);
  csrloc_k<<<NBUK, 256, 0, stream>>>(stage, soff, row_ptr, csr, dinv, N, E, NBUK);

  gemm_k<<<(N + 127) / 128, 256, 0, stream>>>(x, W1, dinv, gu, N);

  const int P1_BLOCKS = 2048;
  prop1_k<<<P1_BLOCKS, 256, 0, stream>>>((const uint4*)gu, row_ptr, csr, dinv, b1,
                                         Wout, (unsigned*)g2u, N, P1_BLOCKS * 4);
  const int P2_BLOCKS = 2048;
  prop2_k<<<P2_BLOCKS, 256, 0, stream>>>(g2u, row_ptr, csr, dinv, bout, out,
                                         N, P2_BLOCKS * 32);
}

// Round 6
// 144.093 us; speedup vs baseline: 11.4885x; 1.0492x over previous
//
#include <hip/hip_runtime.h>

// GCN: out[m,n,o] = (A_hat relu(A_hat (x W1) + b1) W_out[m])[n,o] + b_out[m,o]
// A_hat = D^-1/2 (A + I) D^-1/2.
// R6 structure:
//  - radix partition by 64-node dst-bucket (LDS hists + 2-level scan),
//    scanfix folded into consumers (NBLKB == scan chunk == 256).
//  - g = bf16(dinv * (x@W1)) via MFMA split-bf16: x·W = xh·Wh + xh·Wl + xl·Wh
//    (~fp32 precision; k-permutation inside fragments cancels between A and B).
//  - prop1: full-occupancy gather, 16 lanes x uint4 per row, fused relu +
//    8-col projection (propagation linear in features).
//  - prop2: 2 threads/node, uint2 bf16x4 per edge, fused bias/dinv.

constexpr int CIN = 128;
constexpr int BSHIFT = 6;        // 64 nodes per bucket
constexpr int NBLKB = 256;       // partition blocks == scan chunk size
constexpr int NBUK_MAX = 1024;   // LDS hist capacity (N<=65536)
constexpr int CSR_CAP = 4096;    // LDS bucket-sort capacity (mean ~2048, std ~45)

typedef __attribute__((ext_vector_type(8))) short short8v;
typedef __attribute__((ext_vector_type(4))) float float4v;

__device__ inline unsigned pack_bf16x2(float a, float b) {
  unsigned ua = __float_as_uint(a), ub = __float_as_uint(b);
  ua = (ua + 0x7FFFu + ((ua >> 16) & 1u)) >> 16;
  ub = (ub + 0x7FFFu + ((ub >> 16) & 1u)) >> 16;
  return ua | (ub << 16);
}
__device__ inline float bf_lo(unsigned u) { return __uint_as_float(u << 16); }
__device__ inline float bf_hi(unsigned u) { return __uint_as_float(u & 0xFFFF0000u); }

// ---------- pass A: per-block bucket histogram (LDS only) ----------
__global__ __launch_bounds__(256) void histbuck_k(const int* __restrict__ dst,
    int* __restrict__ blockhist, int E, int nbuk) {
  __shared__ int lh[NBUK_MAX];
  int b = blockIdx.x, t = threadIdx.x;
  for (int k = t; k < nbuk; k += 256) lh[k] = 0;
  __syncthreads();
  int per = (E + gridDim.x - 1) / gridDim.x;
  int s0 = b * per, s1 = min(E, s0 + per);
  for (int i = s0 + t; i < s1; i += 256) atomicAdd(&lh[dst[i] >> BSHIFT], 1);
  __syncthreads();
  for (int k = t; k < nbuk; k += 256) blockhist[k * NBLKB + b] = lh[k];
}

// exclusive scan, blockDim-agnostic (256 or 1024); btot==nullptr for top level
__global__ void scan_k(const int* __restrict__ v_in,
    int* __restrict__ excl_out, int* __restrict__ btot, int n) {
  __shared__ int wsum[16];
  int t = threadIdx.x, l = t & 63, w = t >> 6;
  int nw = blockDim.x >> 6;
  int i = blockIdx.x * blockDim.x + t;
  int v = (i < n) ? v_in[i] : 0;
  int orig = v;
  #pragma unroll
  for (int off = 1; off < 64; off <<= 1) {
    int u = __shfl_up(v, off);
    if (l >= off) v += u;
  }
  if (l == 63) wsum[w] = v;
  __syncthreads();
  int add = 0;
  for (int j = 0; j < nw; ++j) if (j < w) add += wsum[j];
  v += add;
  if (i < n) excl_out[i] = v - orig;
  if (t == (int)blockDim.x - 1 && btot != nullptr) btot[blockIdx.x] = v;
}

// ---------- pass B: write edges to exact (block,bucket) ranges ----------
__global__ __launch_bounds__(256) void stageB_k(const int* __restrict__ src,
    const int* __restrict__ dst, const int* __restrict__ soff,
    const int* __restrict__ boff, unsigned* __restrict__ stage, int E, int nbuk) {
  __shared__ int loff[NBUK_MAX];
  int b = blockIdx.x, t = threadIdx.x;
  for (int k = t; k < nbuk; k += 256) loff[k] = soff[k * NBLKB + b] + boff[k];
  __syncthreads();
  int per = (E + gridDim.x - 1) / gridDim.x;
  int s0 = b * per, s1 = min(E, s0 + per);
  for (int i = s0 + t; i < s1; i += 256) {
    int d = dst[i], s = src[i];
    int pos = atomicAdd(&loff[d >> BSHIFT], 1);
    stage[pos] = (unsigned)s | ((unsigned)(d & 63) << 17);  // src<2^17, dloc 6b
  }
}

// ---------- per-bucket LDS count-sort: stage -> per-node CSR + dinv ----------
__global__ __launch_bounds__(256) void csrloc_k(const unsigned* __restrict__ stage,
    const int* __restrict__ soff, const int* __restrict__ boff,
    int* __restrict__ row_ptr, int* __restrict__ csr,
    float* __restrict__ dinv, int N, int E, int nbuk) {
  __shared__ int cnt64[64], off64[64], cur64[64];
  __shared__ unsigned ebuf[CSR_CAP];
  __shared__ int sbuf[CSR_CAP];
  int k = blockIdx.x, t = threadIdx.x;
  if (t < 64) { cnt64[t] = 0; cur64[t] = 0; }
  __syncthreads();
  int r0 = soff[k * NBLKB] + boff[k];
  int r1 = (k + 1 < nbuk) ? soff[(k + 1) * NBLKB] + boff[k + 1] : E;
  int len = r1 - r0;
  if (len <= CSR_CAP) {
    for (int i = t; i < len; i += 256) {
      unsigned s = stage[r0 + i];
      ebuf[i] = s;
      atomicAdd(&cnt64[s >> 17], 1);
    }
    __syncthreads();
    if (t < 64) {
      int v = cnt64[t], orig = v;
      #pragma unroll
      for (int off = 1; off < 64; off <<= 1) {
        int u = __shfl_up(v, off);
        if (t >= off) v += u;
      }
      off64[t] = v - orig;
      int n = (k << BSHIFT) + t;
      if (n < N) {
        row_ptr[n] = r0 + v - orig;
        dinv[n] = rsqrtf((float)(orig + 1));
      }
      if (k == nbuk - 1 && t == 63) row_ptr[N] = E;
    }
    __syncthreads();
    for (int i = t; i < len; i += 256) {
      unsigned s = ebuf[i];
      int dl = s >> 17;
      int pos = off64[dl] + atomicAdd(&cur64[dl], 1);
      sbuf[pos] = (int)(s & 0x1FFFF);
    }
    __syncthreads();
    for (int i = t; i < len; i += 256) csr[r0 + i] = sbuf[i];
  } else {  // fallback (statistically never at E/N=32)
    for (int i = r0 + t; i < r1; i += 256) atomicAdd(&cnt64[stage[i] >> 17], 1);
    __syncthreads();
    if (t < 64) {
      int v = cnt64[t], orig = v;
      #pragma unroll
      for (int off = 1; off < 64; off <<= 1) {
        int u = __shfl_up(v, off);
        if (t >= off) v += u;
      }
      off64[t] = v - orig;
      int n = (k << BSHIFT) + t;
      if (n < N) {
        row_ptr[n] = r0 + v - orig;
        dinv[n] = rsqrtf((float)(orig + 1));
      }
      if (k == nbuk - 1 && t == 63) row_ptr[N] = E;
    }
    __syncthreads();
    for (int i = r0 + t; i < r1; i += 256) {
      unsigned s = stage[i];
      int dl = s >> 17;
      int pos = r0 + off64[dl] + atomicAdd(&cur64[dl], 1);
      csr[pos] = (int)(s & 0x1FFFF);
    }
  }
}

// ---------- g(bf16) = dinv[n]*(x@W1) via MFMA split-bf16 ----------
__device__ inline void split8(const float* f, short8v& ah, short8v& al) {
  #pragma unroll
  for (int j = 0; j < 8; ++j) {
    unsigned ua = __float_as_uint(f[j]);
    unsigned hb = (ua + 0x7FFFu + ((ua >> 16) & 1u)) >> 16;
    float fh = __uint_as_float(hb << 16);
    float rl = f[j] - fh;
    unsigned ub = __float_as_uint(rl);
    unsigned lb = (ub + 0x7FFFu + ((ub >> 16) & 1u)) >> 16;
    ah[j] = (short)hb;
    al[j] = (short)lb;
  }
}

__global__ __launch_bounds__(256) void gemm_k(const float* __restrict__ x,
    const float* __restrict__ W, const float* __restrict__ dinv,
    unsigned* __restrict__ gu, int nrows) {
  __shared__ unsigned short Bh[16384];  // [kstep][coltile][lane][j] bf16 bits
  __shared__ unsigned short Bl[16384];
  int t = threadIdx.x, l = t & 63, w = t >> 6;
  // stage W split hi/lo into fragment-ready layout
  for (int idx = t; idx < 16384; idx += 256) {
    int k = idx >> 7, col = idx & 127;
    float wv = W[idx];
    unsigned ua = __float_as_uint(wv);
    unsigned hb = (ua + 0x7FFFu + ((ua >> 16) & 1u)) >> 16;
    float fh = __uint_as_float(hb << 16);
    float rl = wv - fh;
    unsigned ub = __float_as_uint(rl);
    unsigned lb = (ub + 0x7FFFu + ((ub >> 16) & 1u)) >> 16;
    int addr = (((k >> 5) * 8 + (col >> 4)) * 64 +
                (((k >> 3) & 3) * 16 + (col & 15))) * 8 + (k & 7);
    Bh[addr] = (unsigned short)hb;
    Bl[addr] = (unsigned short)lb;
  }
  __syncthreads();

  int row0 = blockIdx.x * 128;
  int ct0 = w * 2;                       // wave's two col-tiles
  float4v acc[8][2];
  #pragma unroll
  for (int i = 0; i < 8; ++i) { acc[i][0] = (float4v)0.f; acc[i][1] = (float4v)0.f; }
  int arow = row0 + (l & 15);
  int kln = (l >> 4) * 8;

  for (int ks = 0; ks < 4; ++ks) {
    short8v bh0 = *(short8v*)&Bh[((ks * 8 + ct0) * 64 + l) * 8];
    short8v bh1 = *(short8v*)&Bh[((ks * 8 + ct0 + 1) * 64 + l) * 8];
    short8v bl0 = *(short8v*)&Bl[((ks * 8 + ct0) * 64 + l) * 8];
    short8v bl1 = *(short8v*)&Bl[((ks * 8 + ct0 + 1) * 64 + l) * 8];
    #pragma unroll
    for (int rt = 0; rt < 8; ++rt) {
      int r = arow + rt * 16;
      const float* xp = &x[(size_t)min(r, nrows - 1) * CIN + ks * 32 + kln];
      float f[8];
      *(float4*)&f[0] = *(const float4*)xp;
      *(float4*)&f[4] = *(const float4*)(xp + 4);
      short8v ah, al;
      split8(f, ah, al);
      acc[rt][0] = __builtin_amdgcn_mfma_f32_16x16x32_bf16(ah, bh0, acc[rt][0], 0, 0, 0);
      acc[rt][1] = __builtin_amdgcn_mfma_f32_16x16x32_bf16(ah, bh1, acc[rt][1], 0, 0, 0);
      acc[rt][0] = __builtin_amdgcn_mfma_f32_16x16x32_bf16(ah, bl0, acc[rt][0], 0, 0, 0);
      acc[rt][1] = __builtin_amdgcn_mfma_f32_16x16x32_bf16(ah, bl1, acc[rt][1], 0, 0, 0);
      acc[rt][0] = __builtin_amdgcn_mfma_f32_16x16x32_bf16(al, bh0, acc[rt][0], 0, 0, 0);
      acc[rt][1] = __builtin_amdgcn_mfma_f32_16x16x32_bf16(al, bh1, acc[rt][1], 0, 0, 0);
    }
  }
  // epilogue: D col = l&15, row = 4*(l>>4)+reg [HW-verified layout]
  #pragma unroll
  for (int rt = 0; rt < 8; ++rt) {
    #pragma unroll
    for (int r = 0; r < 4; ++r) {
      int row = row0 + rt * 16 + (l >> 4) * 4 + r;
      bool ok = row < nrows;
      float dv = ok ? dinv[row] : 0.f;
      #pragma unroll
      for (int c = 0; c < 2; ++c) {
        float val = acc[rt][c][r] * dv;
        float other = __shfl_xor(val, 1);
        int col = (ct0 + c) * 16 + (l & 15);
        if (ok && !(l & 1)) gu[(size_t)row * 64 + (col >> 1)] = pack_bf16x2(val, other);
      }
    }
  }
}

// ---------- propagate-1: 16-lane x uint4 row gather + fused epilogue ----------
#define ACC8(U) do { \
  acc[0] += bf_lo((U).x); acc[1] += bf_hi((U).x); \
  acc[2] += bf_lo((U).y); acc[3] += bf_hi((U).y); \
  acc[4] += bf_lo((U).z); acc[5] += bf_hi((U).z); \
  acc[6] += bf_lo((U).w); acc[7] += bf_hi((U).w); } while (0)

__global__ __launch_bounds__(256) void prop1_k(const uint4* __restrict__ g4,
    const int* __restrict__ row_ptr, const int* __restrict__ csr,
    const float* __restrict__ dinv, const float* __restrict__ b1,
    const float* __restrict__ Wout, unsigned* __restrict__ g2w,
    int n_nodes, int n_waves) {
  int l = threadIdx.x & 63;
  int q = l & 15, sub = l >> 4;     // lane q covers cols 8q..8q+7; sub owns j=2sub,2sub+1
  int wid = (blockIdx.x * blockDim.x + threadIdx.x) >> 6;
  float wj0[8], wj1[8], bb[8];
  #pragma unroll
  for (int c = 0; c < 8; ++c) {
    int col = 8 * q + c;
    wj0[c] = Wout[sub * 256 + col * 2];
    wj1[c] = Wout[sub * 256 + col * 2 + 1];
    bb[c] = b1[col];
  }
  for (int n = wid; n < n_nodes; n += n_waves) {
    int start = row_ptr[n], end = row_ptr[n + 1];
    float d = dinv[n];
    float acc[8];
    #pragma unroll
    for (int c = 0; c < 8; ++c) acc[c] = 0.f;
    for (int base = start; base < end; base += 64) {
      int cnt = min(64, end - base);
      int eb = (base + l < end) ? csr[base + l] : 0;
      int i = 0;
      for (; i + 16 <= cnt; i += 16) {
        int s0 = __shfl(eb, i + sub);
        int s1 = __shfl(eb, i + 4 + sub);
        int s2 = __shfl(eb, i + 8 + sub);
        int s3 = __shfl(eb, i + 12 + sub);
        uint4 u0 = g4[s0 * 16 + q];
        uint4 u1 = g4[s1 * 16 + q];
        uint4 u2 = g4[s2 * 16 + q];
        uint4 u3 = g4[s3 * 16 + q];
        ACC8(u0); ACC8(u1); ACC8(u2); ACC8(u3);
      }
      for (; i + 4 <= cnt; i += 4) {
        int s0 = __shfl(eb, i + sub);
        uint4 u0 = g4[s0 * 16 + q];
        ACC8(u0);
      }
      if (i < cnt) {
        int idx = i + sub;
        bool vld = idx < cnt;
        int s0 = __shfl(eb, vld ? idx : i);
        uint4 u0 = g4[s0 * 16 + q];
        if (vld) { ACC8(u0); }
      }
    }
    #pragma unroll
    for (int c = 0; c < 8; ++c) {   // merge the 4 sub-waves
      acc[c] += __shfl_xor(acc[c], 16);
      acc[c] += __shfl_xor(acc[c], 32);
    }
    uint4 us = g4[n * 16 + q];       // self-loop (dinv folded in g)
    ACC8(us);
    float p0 = 0.f, p1 = 0.f;
    #pragma unroll
    for (int c = 0; c < 8; ++c) {
      float y = fmaxf(fmaf(acc[c], d, bb[c]), 0.f);
      p0 = fmaf(y, wj0[c], p0);
      p1 = fmaf(y, wj1[c], p1);
    }
    #pragma unroll
    for (int off = 1; off < 16; off <<= 1) {
      p0 += __shfl_xor(p0, off);
      p1 += __shfl_xor(p1, off);
    }
    if (q == 0) g2w[n * 4 + sub] = pack_bf16x2(d * p0, d * p1);
  }
}

// ---------- propagate-2: 2 threads/node, uint2 bf16x4 per edge ----------
__global__ __launch_bounds__(256) void prop2_k(const uint2* __restrict__ g2v,
    const int* __restrict__ row_ptr, const int* __restrict__ csr,
    const float* __restrict__ dinv, const float* __restrict__ bout,
    float* __restrict__ out, int N) {
  int tid = blockIdx.x * 256 + threadIdx.x;
  int n = tid >> 1, hf = tid & 1;
  if (n >= N) return;
  uint2 us = g2v[n * 2 + hf];      // self-loop
  float a0 = bf_lo(us.x), a1 = bf_hi(us.x);
  float a2 = bf_lo(us.y), a3 = bf_hi(us.y);
  int e = row_ptr[n], e1 = row_ptr[n + 1];
  for (; e + 4 <= e1; e += 4) {
    int i0 = csr[e], i1 = csr[e + 1], i2 = csr[e + 2], i3 = csr[e + 3];
    uint2 u0 = g2v[i0 * 2 + hf], u1 = g2v[i1 * 2 + hf];
    uint2 u2 = g2v[i2 * 2 + hf], u3 = g2v[i3 * 2 + hf];
    a0 += (bf_lo(u0.x) + bf_lo(u1.x)) + (bf_lo(u2.x) + bf_lo(u3.x));
    a1 += (bf_hi(u0.x) + bf_hi(u1.x)) + (bf_hi(u2.x) + bf_hi(u3.x));
    a2 += (bf_lo(u0.y) + bf_lo(u1.y)) + (bf_lo(u2.y) + bf_lo(u3.y));
    a3 += (bf_hi(u0.y) + bf_hi(u1.y)) + (bf_hi(u2.y) + bf_hi(u3.y));
  }
  for (; e < e1; ++e) {
    uint2 u = g2v[csr[e] * 2 + hf];
    a0 += bf_lo(u.x); a1 += bf_hi(u.x);
    a2 += bf_lo(u.y); a3 += bf_hi(u.y);
  }
  float d = dinv[n];
  float2 o0 = make_float2(fmaf(d, a0, bout[hf * 4 + 0]), fmaf(d, a1, bout[hf * 4 + 1]));
  float2 o1 = make_float2(fmaf(d, a2, bout[hf * 4 + 2]), fmaf(d, a3, bout[hf * 4 + 3]));
  *(float2*)&out[(size_t)(hf * 2 + 0) * (2 * N) + 2 * n] = o0;
  *(float2*)&out[(size_t)(hf * 2 + 1) * (2 * N) + 2 * n] = o1;
}

extern "C" void kernel_launch(void* const* d_in, const int* in_sizes, int n_in,
                              void* d_out, int out_size, void* d_ws, size_t ws_size,
                              hipStream_t stream) {
  const float* x    = (const float*)d_in[0];
  const int*   ei   = (const int*)d_in[1];
  const float* W1   = (const float*)d_in[2];
  const float* b1   = (const float*)d_in[3];
  const float* Wout = (const float*)d_in[4];
  const float* bout = (const float*)d_in[5];
  float* out = (float*)d_out;

  const int N = in_sizes[0] / CIN;     // 50000
  const int E = in_sizes[1] / 2;       // 1600000
  const int* srcp = ei;
  const int* dstp = ei + E;
  const int NBUK = (N + 63) >> BSHIFT; // 782
  const int NSC = NBUK * NBLKB;        // 200192 scan entries

  char* ws = (char*)d_ws;
  size_t off = 0;
  auto alloc = [&](size_t bytes) -> void* {
    void* p = ws + off;
    off = (off + bytes + 511) & ~(size_t)511;
    return p;
  };
  unsigned*       gu        = (unsigned*)alloc((size_t)N * 64 * 4);      // bf16 g
  unsigned short* g2u       = (unsigned short*)alloc((size_t)N * 8 * 2); // bf16 g2
  float*          dinv      = (float*)alloc((size_t)N * 4);
  int*            blockhist = (int*)alloc((size_t)NSC * 4);
  int*            soff      = (int*)alloc((size_t)NSC * 4);
  int*            btot      = (int*)alloc((size_t)NBUK_MAX * 4);
  int*            boff      = (int*)alloc((size_t)NBUK_MAX * 4);
  int*            row_ptr   = (int*)alloc((size_t)(N + 1) * 4);
  int*            csr       = (int*)alloc((size_t)E * 4);
  unsigned*       stage     = (unsigned*)alloc((size_t)E * 4);
  (void)ws_size; (void)n_in; (void)out_size;

  histbuck_k<<<NBLKB, 256, 0, stream>>>(dstp, blockhist, E, NBUK);
  scan_k<<<NBUK, 256, 0, stream>>>(blockhist, soff, btot, NSC);     // level 1
  scan_k<<<1, 1024, 0, stream>>>(btot, boff, nullptr, NBUK);        // level 2
  stageB_k<<<NBLKB, 256, 0, stream>>>(srcp, dstp, soff, boff, stage, E, NBUK);
  csrloc_k<<<NBUK, 256, 0, stream>>>(stage, soff, boff, row_ptr, csr, dinv, N, E, NBUK);

  gemm_k<<<(N + 127) / 128, 256, 0, stream>>>(x, W1, dinv, gu, N);

  const int P1_BLOCKS = 2048;
  prop1_k<<<P1_BLOCKS, 256, 0, stream>>>((const uint4*)gu, row_ptr, csr, dinv, b1,
                                         Wout, (unsigned*)g2u, N, P1_BLOCKS * 4);
  prop2_k<<<(2 * N + 255) / 256, 256, 0, stream>>>((const uint2*)g2u, row_ptr, csr,
                                                   dinv, bout, out, N);
}